// Round 8
// baseline (148.264 us; speedup 1.0000x reference)
//
#include <hip/hip_runtime.h>
#include <hip/hip_bf16.h>
#include <stdint.h>
#include <type_traits>

#define BSAMP 8192
#define NCLS 400
#define DIM 768
#define LOGITS_SIZE (16384LL * 400LL)
#define GEMM_BLOCKS 256     // one 64-row band per block, FULL N=400 -> A read exactly once
#define MASK_BLOCKS 4096    // 4 (sample,box) pairs per block, 1 per wave
#define W_ELEMS (NCLS * DIM)

typedef __attribute__((ext_vector_type(8))) short short8;
typedef __attribute__((ext_vector_type(4))) float floatx4;

// fp32 -> bf16 round-half-up, two at a time: 2 adds + 1 v_perm
__device__ inline unsigned int packbf(float a, float b) {
    unsigned int ua = __float_as_uint(a) + 0x8000u;
    unsigned int ub = __float_as_uint(b) + 0x8000u;
    return __builtin_amdgcn_perm(ub, ua, 0x07060302u);  // [ua.b2,ua.b3,ub.b2,ub.b3]
}

__device__ inline short8 cvt8(float4 lo, float4 hi) {
    union { unsigned int u[4]; short8 s; } r;
    r.u[0] = packbf(lo.x, lo.y);
    r.u[1] = packbf(lo.z, lo.w);
    r.u[2] = packbf(hi.x, hi.y);
    r.u[3] = packbf(hi.z, hi.w);
    return r.s;
}

// async global->LDS DMA, 16 B/lane, dest = wave-uniform base + lane*16.
__device__ inline void gload16(const void* g, void* l) {
    __builtin_amdgcn_global_load_lds((const __attribute__((address_space(1))) void*)g,
                                     (__attribute__((address_space(3))) void*)l, 16, 0, 0);
}

// W fp32 -> bf16 pre-convert (0.6 MB into d_ws); re-run every launch (ws re-poisoned)
__global__ void cvtW_kernel(const float* __restrict__ W, unsigned short* __restrict__ ws) {
    int i = (blockIdx.x * 256 + threadIdx.x) * 4;
    if (i < W_ELEMS) {
        float4 f = *(const float4*)(W + i);
        uint2 r;
        r.x = packbf(f.x, f.y);
        r.y = packbf(f.z, f.w);
        *(uint2*)(ws + i) = r;
    }
}

// 2x2 tap: identical expressions to the reference's inner bilinear (coord chain hoisted)
__device__ inline float tap4(const float* m14, int r0, int c0, float fy, float fx) {
    int r1 = min(r0 + 1, 13);
    int c1 = min(c0 + 1, 13);
    float g00 = m14[r0 * 14 + c0];
    float g01 = m14[r0 * 14 + c1];
    float g10 = m14[r1 * 14 + c0];
    float g11 = m14[r1 * 14 + c1];
    return g00 * (1.f - fy) * (1.f - fx) + g01 * (1.f - fy) * fx +
           g10 * fy * (1.f - fx) + g11 * fy * fx;
}

// ============== GEMM kernel: 64(M) x 400(N), A read ONCE, 512 threads = 2 waves/SIMD ==============
// R7 post-mortem: A-read-once structure works (gemm < 42 us) but 256 threads = 1 wave/SIMD left
// every ds_read/MFMA/barrier latency fully exposed. 8 waves now: wave w owns M-rows (w&3)*16 and
// N-half (w>>2): tiles 0..12 (cols 0..207) or 13..24 (cols 208..399). Wave pairs (w, w+4) load
// identical A fragments -> L1 serves the duplicate; HBM A-traffic stays 50 MB.
// B LDS: [buf][400 rows][64 k] bf16, per-64B-slab XOR-chunk swizzle (proven, 0 conflicts).
struct GemmSm { unsigned short B[2][400 * 64]; };   // 102400 B -> 1 block/CU (grid=256, by design)

template <bool USE_WS>
__global__ __launch_bounds__(512, 2) void gemm_kernel(const float* __restrict__ E,
                                                      const float* __restrict__ W,
                                                      const float* __restrict__ bias,
                                                      const unsigned short* __restrict__ wsW,
                                                      float* __restrict__ out) {
    __shared__ __align__(16) GemmSm sg;

    const int bx = blockIdx.x;
    const int t  = threadIdx.x;
    const int wv = t >> 6, ln = t & 63;

    const int m0 = bx * 64;                 // unique band: A element read exactly once per kernel
    const int quad = ln >> 4, l16 = ln & 15;

    // N-half split: lower 13 tiles (208 cols) / upper 12 tiles (192 cols)
    const int half    = wv >> 2;            // 0 or 1
    const int NT      = half ? 12 : 13;     // tiles this wave owns
    const int colBase = half ? 208 : 0;

    // A frag source: lane (quad,l16) needs row (wv&3)*16+l16, k = it*32 + quad*8..+7
    const float* aptr = E + (size_t)(m0 + (wv & 3) * 16 + l16) * DIM + quad * 8;

    floatx4 acc[13];
#pragma unroll
    for (int ni = 0; ni < 13; ++ni) acc[ni] = (floatx4){0.f, 0.f, 0.f, 0.f};

    if constexpr (USE_WS) {
        // stage super s = k-slab [s*64, s*64+64) for all 400 rows: 51.2 KB, 50 gload16-chunks.
        // chunk c covers rows c*8..c*8+7 (128 B/row); lane ln -> row c*8+(ln>>3), 16B-chunk ln&7.
        // within each 64-B half-row (slab), phys 16B-chunk q holds logical q^((row>>1)&3).
        auto stageB = [&](int s, int buf) {
            unsigned short* base = &sg.B[buf][0];
            for (int c = wv; c < 50; c += 8) {
                int row = c * 8 + (ln >> 3);
                const unsigned short* src = wsW + (size_t)row * DIM + s * 64 +
                                            ((ln >> 2) & 1) * 32 +
                                            8 * ((ln & 3) ^ ((row >> 1) & 3));
                gload16(src, base + c * 512);
            }
        };

        float4 pf[2][2];   // 2-deep A lookahead
        auto LDA = [&](int it, int d) {
            pf[d][0] = *(const float4*)(aptr + it * 32);
            pf[d][1] = *(const float4*)(aptr + it * 32 + 4);
        };

        stageB(0, 0);
        LDA(0, 0);
        LDA(1, 1);
        __syncthreads();   // drain prologue (super 0 + A0/A1 regs)

#pragma unroll
        for (int s = 0; s < 12; ++s) {
            if (s < 11) stageB(s + 1, (s + 1) & 1);   // 2 k-iters of cover
#pragma unroll
            for (int kk = 0; kk < 2; ++kk) {
                const int it = s * 2 + kk;
                const int pb = it & 1;
                short8 af = cvt8(pf[pb][0], pf[pb][1]);
                if (it < 22) LDA(it + 2, pb);          // issue early
                __builtin_amdgcn_sched_barrier(0);     // pin: loads stay issued here
                const unsigned short* bb = &sg.B[s & 1][0];
#pragma unroll
                for (int ni = 0; ni < 13; ++ni) {
                    if (ni < NT) {                     // wave-uniform guard (upper half: 12)
                        int row = colBase + ni * 16 + l16;
                        short8 bfr = *(const short8*)(bb + row * 64 + kk * 32 +
                                                      8 * (quad ^ ((row >> 1) & 3)));
                        acc[ni] = __builtin_amdgcn_mfma_f32_16x16x32_bf16(af, bfr, acc[ni], 0, 0, 0);
                    }
                }
            }
            __syncthreads();   // end of super: readers of buf[s&1] done; drains stage(s+1)
        }
    } else {
        // fallback (no workspace): B per-lane from global fp32
        for (int it = 0; it < 24; ++it) {
            short8 af = cvt8(*(const float4*)(aptr + it * 32), *(const float4*)(aptr + it * 32 + 4));
#pragma unroll
            for (int ni = 0; ni < 13; ++ni) {
                if (ni < NT) {
                    const float* wp = W + (size_t)(colBase + ni * 16 + l16) * DIM + it * 32 + quad * 8;
                    short8 bfr = cvt8(*(const float4*)wp, *(const float4*)(wp + 4));
                    acc[ni] = __builtin_amdgcn_mfma_f32_16x16x32_bf16(af, bfr, acc[ni], 0, 0, 0);
                }
            }
        }
    }

    // epilogue: C/D layout col=lane&15, row=quad*4+reg (HW-verified).
    const int rowBase = m0 + (wv & 3) * 16 + quad * 4;
#pragma unroll
    for (int ni = 0; ni < 13; ++ni) {
        if (ni < NT) {
            int col = colBase + ni * 16 + l16;
            float bv = bias[col];
#pragma unroll
            for (int r = 0; r < 4; ++r) {
                out[(size_t)(rowBase + r) * NCLS + col] = acc[ni][r] + bv;
            }
        }
    }
}

// ===================== mask kernel: 4 (sample,box) pairs per block, 1 per wave =====================
struct MaskSm { float m14[4][208]; float a7[4][56]; float mv[4][56]; };  // 5120 B

__global__ __launch_bounds__(256, 8) void mask_kernel(const float* __restrict__ attn,
                                                      const int* __restrict__ pos,
                                                      float* __restrict__ out) {
    __shared__ __align__(16) MaskSm sm;

    const int bx = blockIdx.x;
    const int t  = threadIdx.x;
    const int wv = t >> 6, ln = t & 63;

    // pairing: waves (2k, 2k+1) hold (b, o=0) and (b, o=1) of the SAME sample ->
    // the 784-B attn row is fetched from HBM once per block instead of twice globally.
    const int p = bx * 4 + wv;   // 0..16383
    const int b = p >> 1;
    const int o = p & 1;
    float* m14 = sm.m14[wv];

    for (int i = ln; i < 196; i += 64) m14[i] = attn[(size_t)b * 196 + i];

    const int* pb = pos + (size_t)b * 12;
    const float topf  = (float)(pb[o * 4 + 0] - pb[8]);
    const float leftf = (float)(pb[o * 4 + 1] - pb[9]);
    const float oH = (float)pb[o * 4 + 2];
    const float oW = (float)pb[o * 4 + 3];
    const float eH = (float)pb[10];
    const float eW = (float)pb[11];
    __syncthreads();

    const int i7 = ln / 7, j7 = ln - i7 * 7;
    if (ln < 49) {
        // hoisted coordinate chains (identical expressions to reference; computed once)
        int   cI[2][2];  float cF[2][2];  float wxs[2];   // [dx][which X]
        int   rI[2][2];  float rF[2][2];  float wys[2];   // [dy][which Y]
#pragma unroll
        for (int dx = 0; dx < 2; ++dx) {
            int ox = 2 * j7 + dx;
            float tx = fmaxf((ox + 0.5f) * oW / 14.0f - 0.5f, 0.0f);
            float x0 = floorf(tx);
            float x1 = fminf(x0 + 1.0f, oW - 1.0f);
            wxs[dx] = tx - x0;
            float X0 = leftf + x0, X1 = leftf + x1;
            float sx0 = fmaxf((X0 + 0.5f) * 14.0f / eW - 0.5f, 0.0f);
            float c0f = floorf(sx0);
            cI[dx][0] = (int)c0f; cF[dx][0] = sx0 - c0f;
            float sx1 = fmaxf((X1 + 0.5f) * 14.0f / eW - 0.5f, 0.0f);
            float c1f = floorf(sx1);
            cI[dx][1] = (int)c1f; cF[dx][1] = sx1 - c1f;
        }
#pragma unroll
        for (int dy = 0; dy < 2; ++dy) {
            int oy = 2 * i7 + dy;
            float ty = fmaxf((oy + 0.5f) * oH / 14.0f - 0.5f, 0.0f);
            float y0 = floorf(ty);
            float y1 = fminf(y0 + 1.0f, oH - 1.0f);
            wys[dy] = ty - y0;
            float Y0 = topf + y0, Y1 = topf + y1;
            float sy0 = fmaxf((Y0 + 0.5f) * 14.0f / eH - 0.5f, 0.0f);
            float r0f = floorf(sy0);
            rI[dy][0] = (int)r0f; rF[dy][0] = sy0 - r0f;
            float sy1 = fmaxf((Y1 + 0.5f) * 14.0f / eH - 0.5f, 0.0f);
            float r1f = floorf(sy1);
            rI[dy][1] = (int)r1f; rF[dy][1] = sy1 - r1f;
        }

        float s = 0.f;
#pragma unroll
        for (int dy = 0; dy < 2; ++dy) {
            float wy = wys[dy];
#pragma unroll
            for (int dx = 0; dx < 2; ++dx) {
                float wx = wxs[dx];
                float v00 = tap4(m14, rI[dy][0], cI[dx][0], rF[dy][0], cF[dx][0]);
                float v01 = tap4(m14, rI[dy][0], cI[dx][1], rF[dy][0], cF[dx][1]);
                float v10 = tap4(m14, rI[dy][1], cI[dx][0], rF[dy][1], cF[dx][0]);
                float v11 = tap4(m14, rI[dy][1], cI[dx][1], rF[dy][1], cF[dx][1]);
                float cm = v00 * (1.f - wy) * (1.f - wx) + v01 * (1.f - wy) * wx +
                           v10 * wy * (1.f - wx) + v11 * wy * wx;
                s += cm;
            }
        }
        sm.a7[wv][ln] = s * 0.25f;
    }
    __syncthreads();

    if (ln < 49) {  // stable top-25 rank (jax.lax.top_k tie-break to lower index)
        float mine = sm.a7[wv][ln];
        int cnt = 0;
#pragma unroll 7
        for (int s2 = 0; s2 < 49; ++s2) {
            float v = sm.a7[wv][s2];
            cnt += (v > mine) || (v == mine && s2 < ln);
        }
        sm.mv[wv][ln] = (cnt < 25) ? 0.0f : 1.0f;
    }
    __syncthreads();

    float* ob = out + LOGITS_SIZE + (size_t)(o * BSAMP + b) * 196;
    for (int i = ln; i < 196; i += 64) {
        int oy = i / 14, ox = i - oy * 14;
        ob[i] = sm.mv[wv][(oy >> 1) * 7 + (ox >> 1)];
    }
}

extern "C" void kernel_launch(void* const* d_in, const int* in_sizes, int n_in,
                              void* d_out, int out_size, void* d_ws, size_t ws_size,
                              hipStream_t stream) {
    const float* attn = (const float*)d_in[0];
    const int*   pos  = (const int*)d_in[1];
    const float* E    = (const float*)d_in[2];
    const float* W    = (const float*)d_in[3];
    const float* bias = (const float*)d_in[4];
    float* out = (float*)d_out;

    if (ws_size >= (size_t)W_ELEMS * 2) {
        unsigned short* ws = (unsigned short*)d_ws;
        cvtW_kernel<<<300, 256, 0, stream>>>(W, ws);
        gemm_kernel<true><<<GEMM_BLOCKS, 512, 0, stream>>>(E, W, bias, ws, out);
    } else {
        gemm_kernel<false><<<GEMM_BLOCKS, 512, 0, stream>>>(E, W, bias, nullptr, out);
    }
    mask_kernel<<<MASK_BLOCKS, 256, 0, stream>>>(attn, pos, out);
}

// Round 9
// 146.500 us; speedup vs baseline: 1.0120x; 1.0120x over previous
//
#include <hip/hip_runtime.h>
#include <hip/hip_bf16.h>
#include <stdint.h>
#include <type_traits>

#define BSAMP 8192
#define NCLS 400
#define DIM 768
#define LOGITS_SIZE (16384LL * 400LL)
#define GEMM_BLOCKS 256     // one 64-row band per block, FULL N=400 -> A read exactly once
#define MASK_BLOCKS 4096    // 4 (sample,box) pairs per block, 1 per wave
#define W_ELEMS (NCLS * DIM)

typedef __attribute__((ext_vector_type(8))) short short8;
typedef __attribute__((ext_vector_type(4))) float floatx4;

// fp32 -> bf16 round-half-up, two at a time: 2 adds + 1 v_perm
__device__ inline unsigned int packbf(float a, float b) {
    unsigned int ua = __float_as_uint(a) + 0x8000u;
    unsigned int ub = __float_as_uint(b) + 0x8000u;
    return __builtin_amdgcn_perm(ub, ua, 0x07060302u);  // [ua.b2,ua.b3,ub.b2,ub.b3]
}

__device__ inline short8 cvt8(float4 lo, float4 hi) {
    union { unsigned int u[4]; short8 s; } r;
    r.u[0] = packbf(lo.x, lo.y);
    r.u[1] = packbf(lo.z, lo.w);
    r.u[2] = packbf(hi.x, hi.y);
    r.u[3] = packbf(hi.z, hi.w);
    return r.s;
}

// async global->LDS DMA, 16 B/lane, dest = wave-uniform base + lane*16.
__device__ inline void gload16(const void* g, void* l) {
    __builtin_amdgcn_global_load_lds((const __attribute__((address_space(1))) void*)g,
                                     (__attribute__((address_space(3))) void*)l, 16, 0, 0);
}

// W fp32 -> bf16 pre-convert (0.6 MB into d_ws); re-run every launch (ws re-poisoned)
__global__ void cvtW_kernel(const float* __restrict__ W, unsigned short* __restrict__ ws) {
    int i = (blockIdx.x * 256 + threadIdx.x) * 4;
    if (i < W_ELEMS) {
        float4 f = *(const float4*)(W + i);
        uint2 r;
        r.x = packbf(f.x, f.y);
        r.y = packbf(f.z, f.w);
        *(uint2*)(ws + i) = r;
    }
}

// 2x2 tap: identical expressions to the reference's inner bilinear (coord chain hoisted)
__device__ inline float tap4(const float* m14, int r0, int c0, float fy, float fx) {
    int r1 = min(r0 + 1, 13);
    int c1 = min(c0 + 1, 13);
    float g00 = m14[r0 * 14 + c0];
    float g01 = m14[r0 * 14 + c1];
    float g10 = m14[r1 * 14 + c0];
    float g11 = m14[r1 * 14 + c1];
    return g00 * (1.f - fy) * (1.f - fx) + g01 * (1.f - fy) * fx +
           g10 * fy * (1.f - fx) + g11 * fy * fx;
}

// ============== GEMM kernel: 64(M) x 400(N), A read ONCE, all-LDS operands, T3 schedule =============
// R8 post-mortem: __syncthreads' vmcnt(0)+lgkm(0) drain, plus compiler waits for the A-register
// loads interleaved in the same vmcnt queue, serialize every super. Fix (guide §5.5 T3, proven):
// ALL loop loads are global_load_lds (A staged through LDS too -> no VGPR loads in loop), raw
// s_barrier, explicit own-wave vmcnt(0) BEFORE the barrier (=> cross-wave completion after it),
// issued a full compute-phase earlier -> ~0 drain stall.
// B LDS: [buf][400 rows][64 k] bf16, per-64B-slab XOR 16B-chunk swizzle (proven, 0 conflicts).
// A LDS: [buf][64 rows][64 k] fp32; row r: phys 16B-unit u holds logical unit u^(r&15).
struct GemmSm {
    unsigned short B[2][400 * 64];   // 102400 B
    float          A[2][64 * 64];    //  32768 B  -> total 135168 B, 1 block/CU (grid = #CUs)
};

template <bool USE_WS>
__global__ __launch_bounds__(512, 2) void gemm_kernel(const float* __restrict__ E,
                                                      const float* __restrict__ W,
                                                      const float* __restrict__ bias,
                                                      const unsigned short* __restrict__ wsW,
                                                      float* __restrict__ out) {
    __shared__ __align__(16) GemmSm sg;

    const int bx = blockIdx.x;
    const int t  = threadIdx.x;
    const int wv = t >> 6, ln = t & 63;

    const int m0 = bx * 64;                 // unique band: A element read exactly once per kernel
    const int quad = ln >> 4, l16 = ln & 15;

    // N-half split: lower 13 tiles (208 cols) / upper 12 tiles (192 cols)
    const int half    = wv >> 2;            // 0 or 1
    const int NT      = half ? 12 : 13;     // tiles this wave owns
    const int colBase = half ? 208 : 0;

    floatx4 acc[13];
#pragma unroll
    for (int ni = 0; ni < 13; ++ni) acc[ni] = (floatx4){0.f, 0.f, 0.f, 0.f};

    if constexpr (USE_WS) {
        // ---- staging: one k-slab [s*64, s*64+64) per super ----
        // B: 50 chunks of 1 KB (8 rows x 128 B); waves 0..5 own 6 chunks, waves 6..7 own 7.
        // A: 16 chunks of 1 KB (4 rows x 256 B); every wave owns 2.
        auto stageAB = [&](int s, int buf) {
            // A chunks
            float* adst = &sg.A[buf][0];
#pragma unroll
            for (int i = 0; i < 2; ++i) {
                int c = wv * 2 + i;
                int r = c * 4 + (ln >> 4);                 // 0..63
                int u = ln & 15;
                const float* src = E + (size_t)(m0 + r) * DIM + s * 64 + 4 * (u ^ (r & 15));
                gload16(src, adst + c * 256 + ln * 4);     // dest = base + lane*16B (linear)
            }
            // B chunks (identical proven mapping; only ownership re-split)
            unsigned short* bdst = &sg.B[buf][0];
            if (wv < 6) {
#pragma unroll
                for (int i = 0; i < 6; ++i) {
                    int c = wv * 6 + i;
                    int row = c * 8 + (ln >> 3);
                    const unsigned short* src = wsW + (size_t)row * DIM + s * 64 +
                                                ((ln >> 2) & 1) * 32 +
                                                8 * ((ln & 3) ^ ((row >> 1) & 3));
                    gload16(src, bdst + c * 512);
                }
            } else {
#pragma unroll
                for (int i = 0; i < 7; ++i) {
                    int c = 36 + (wv - 6) * 7 + i;
                    int row = c * 8 + (ln >> 3);
                    const unsigned short* src = wsW + (size_t)row * DIM + s * 64 +
                                                ((ln >> 2) & 1) * 32 +
                                                8 * ((ln & 3) ^ ((row >> 1) & 3));
                    gload16(src, bdst + c * 512);
                }
            }
        };

        stageAB(0, 0);
        asm volatile("s_waitcnt vmcnt(0)" ::: "memory");   // prologue drain (once)
        __builtin_amdgcn_s_barrier();
        __builtin_amdgcn_sched_barrier(0);

        const int arow = (wv & 3) * 16 + l16;              // this lane's A row

#pragma unroll
        for (int s = 0; s < 12; ++s) {
            if (s < 11) stageAB(s + 1, (s + 1) & 1);       // full compute-phase of cover
            __builtin_amdgcn_sched_barrier(0);             // pin issue point

            const unsigned short* bb = &sg.B[s & 1][0];
            const float*          ab = &sg.A[s & 1][0];
#pragma unroll
            for (int kk = 0; kk < 2; ++kk) {
                // A frag from LDS: logical units L0,L0+1; phys = logical ^ l16 (conflict-free)
                const int L0 = kk * 8 + quad * 2;
                float4 lo = *(const float4*)(ab + arow * 64 + ((L0)     ^ l16) * 4);
                float4 hi = *(const float4*)(ab + arow * 64 + ((L0 + 1) ^ l16) * 4);
                short8 af = cvt8(lo, hi);
#pragma unroll
                for (int ni = 0; ni < 13; ++ni) {
                    if (ni < NT) {                          // wave-uniform guard
                        int row = colBase + ni * 16 + l16;
                        short8 bfr = *(const short8*)(bb + row * 64 + kk * 32 +
                                                      8 * (quad ^ ((row >> 1) & 3)));
                        acc[ni] = __builtin_amdgcn_mfma_f32_16x16x32_bf16(af, bfr, acc[ni], 0, 0, 0);
                    }
                }
            }

            // T3 tail: own-wave staging done BEFORE barrier -> after barrier, ALL waves' writes
            // are complete. Raw s_barrier = no implicit drain; vmcnt(0) here is ~free (issued
            // one full super earlier).
            asm volatile("s_waitcnt vmcnt(0)" ::: "memory");
            __builtin_amdgcn_s_barrier();
            __builtin_amdgcn_sched_barrier(0);
        }
    } else {
        // fallback (no workspace): B per-lane from global fp32
        const float* aptr = E + (size_t)(m0 + (wv & 3) * 16 + l16) * DIM + quad * 8;
        for (int it = 0; it < 24; ++it) {
            short8 af = cvt8(*(const float4*)(aptr + it * 32), *(const float4*)(aptr + it * 32 + 4));
#pragma unroll
            for (int ni = 0; ni < 13; ++ni) {
                if (ni < NT) {
                    const float* wp = W + (size_t)(colBase + ni * 16 + l16) * DIM + it * 32 + quad * 8;
                    short8 bfr = cvt8(*(const float4*)wp, *(const float4*)(wp + 4));
                    acc[ni] = __builtin_amdgcn_mfma_f32_16x16x32_bf16(af, bfr, acc[ni], 0, 0, 0);
                }
            }
        }
    }

    // epilogue: C/D layout col=lane&15, row=quad*4+reg (HW-verified).
    const int rowBase = m0 + (wv & 3) * 16 + quad * 4;
#pragma unroll
    for (int ni = 0; ni < 13; ++ni) {
        if (ni < NT) {
            int col = colBase + ni * 16 + l16;
            float bv = bias[col];
#pragma unroll
            for (int r = 0; r < 4; ++r) {
                out[(size_t)(rowBase + r) * NCLS + col] = acc[ni][r] + bv;
            }
        }
    }
}

// ===================== mask kernel: 4 (sample,box) pairs per block, 1 per wave =====================
struct MaskSm { float m14[4][208]; float a7[4][56]; float mv[4][56]; };  // 5120 B

__global__ __launch_bounds__(256, 8) void mask_kernel(const float* __restrict__ attn,
                                                      const int* __restrict__ pos,
                                                      float* __restrict__ out) {
    __shared__ __align__(16) MaskSm sm;

    const int bx = blockIdx.x;
    const int t  = threadIdx.x;
    const int wv = t >> 6, ln = t & 63;

    // pairing: waves (2k, 2k+1) hold (b, o=0) and (b, o=1) of the SAME sample ->
    // the 784-B attn row is fetched from HBM once per block instead of twice globally.
    const int p = bx * 4 + wv;   // 0..16383
    const int b = p >> 1;
    const int o = p & 1;
    float* m14 = sm.m14[wv];

    for (int i = ln; i < 196; i += 64) m14[i] = attn[(size_t)b * 196 + i];

    const int* pb = pos + (size_t)b * 12;
    const float topf  = (float)(pb[o * 4 + 0] - pb[8]);
    const float leftf = (float)(pb[o * 4 + 1] - pb[9]);
    const float oH = (float)pb[o * 4 + 2];
    const float oW = (float)pb[o * 4 + 3];
    const float eH = (float)pb[10];
    const float eW = (float)pb[11];
    __syncthreads();

    const int i7 = ln / 7, j7 = ln - i7 * 7;
    if (ln < 49) {
        // hoisted coordinate chains (identical expressions to reference; computed once)
        int   cI[2][2];  float cF[2][2];  float wxs[2];   // [dx][which X]
        int   rI[2][2];  float rF[2][2];  float wys[2];   // [dy][which Y]
#pragma unroll
        for (int dx = 0; dx < 2; ++dx) {
            int ox = 2 * j7 + dx;
            float tx = fmaxf((ox + 0.5f) * oW / 14.0f - 0.5f, 0.0f);
            float x0 = floorf(tx);
            float x1 = fminf(x0 + 1.0f, oW - 1.0f);
            wxs[dx] = tx - x0;
            float X0 = leftf + x0, X1 = leftf + x1;
            float sx0 = fmaxf((X0 + 0.5f) * 14.0f / eW - 0.5f, 0.0f);
            float c0f = floorf(sx0);
            cI[dx][0] = (int)c0f; cF[dx][0] = sx0 - c0f;
            float sx1 = fmaxf((X1 + 0.5f) * 14.0f / eW - 0.5f, 0.0f);
            float c1f = floorf(sx1);
            cI[dx][1] = (int)c1f; cF[dx][1] = sx1 - c1f;
        }
#pragma unroll
        for (int dy = 0; dy < 2; ++dy) {
            int oy = 2 * i7 + dy;
            float ty = fmaxf((oy + 0.5f) * oH / 14.0f - 0.5f, 0.0f);
            float y0 = floorf(ty);
            float y1 = fminf(y0 + 1.0f, oH - 1.0f);
            wys[dy] = ty - y0;
            float Y0 = topf + y0, Y1 = topf + y1;
            float sy0 = fmaxf((Y0 + 0.5f) * 14.0f / eH - 0.5f, 0.0f);
            float r0f = floorf(sy0);
            rI[dy][0] = (int)r0f; rF[dy][0] = sy0 - r0f;
            float sy1 = fmaxf((Y1 + 0.5f) * 14.0f / eH - 0.5f, 0.0f);
            float r1f = floorf(sy1);
            rI[dy][1] = (int)r1f; rF[dy][1] = sy1 - r1f;
        }

        float s = 0.f;
#pragma unroll
        for (int dy = 0; dy < 2; ++dy) {
            float wy = wys[dy];
#pragma unroll
            for (int dx = 0; dx < 2; ++dx) {
                float wx = wxs[dx];
                float v00 = tap4(m14, rI[dy][0], cI[dx][0], rF[dy][0], cF[dx][0]);
                float v01 = tap4(m14, rI[dy][0], cI[dx][1], rF[dy][0], cF[dx][1]);
                float v10 = tap4(m14, rI[dy][1], cI[dx][0], rF[dy][1], cF[dx][0]);
                float v11 = tap4(m14, rI[dy][1], cI[dx][1], rF[dy][1], cF[dx][1]);
                float cm = v00 * (1.f - wy) * (1.f - wx) + v01 * (1.f - wy) * wx +
                           v10 * wy * (1.f - wx) + v11 * wy * wx;
                s += cm;
            }
        }
        sm.a7[wv][ln] = s * 0.25f;
    }
    __syncthreads();

    if (ln < 49) {  // stable top-25 rank (jax.lax.top_k tie-break to lower index)
        float mine = sm.a7[wv][ln];
        int cnt = 0;
#pragma unroll 7
        for (int s2 = 0; s2 < 49; ++s2) {
            float v = sm.a7[wv][s2];
            cnt += (v > mine) || (v == mine && s2 < ln);
        }
        sm.mv[wv][ln] = (cnt < 25) ? 0.0f : 1.0f;
    }
    __syncthreads();

    float* ob = out + LOGITS_SIZE + (size_t)(o * BSAMP + b) * 196;
    for (int i = ln; i < 196; i += 64) {
        int oy = i / 14, ox = i - oy * 14;
        ob[i] = sm.mv[wv][(oy >> 1) * 7 + (ox >> 1)];
    }
}

extern "C" void kernel_launch(void* const* d_in, const int* in_sizes, int n_in,
                              void* d_out, int out_size, void* d_ws, size_t ws_size,
                              hipStream_t stream) {
    const float* attn = (const float*)d_in[0];
    const int*   pos  = (const int*)d_in[1];
    const float* E    = (const float*)d_in[2];
    const float* W    = (const float*)d_in[3];
    const float* bias = (const float*)d_in[4];
    float* out = (float*)d_out;

    if (ws_size >= (size_t)W_ELEMS * 2) {
        unsigned short* ws = (unsigned short*)d_ws;
        cvtW_kernel<<<300, 256, 0, stream>>>(W, ws);
        gemm_kernel<true><<<GEMM_BLOCKS, 512, 0, stream>>>(E, W, bias, ws, out);
    } else {
        gemm_kernel<false><<<GEMM_BLOCKS, 512, 0, stream>>>(E, W, bias, nullptr, out);
    }
    mask_kernel<<<MASK_BLOCKS, 256, 0, stream>>>(attn, pos, out);
}